// Round 12
// baseline (152.545 us; speedup 1.0000x reference)
//
#include <hip/hip_runtime.h>
#include <hip/hip_bf16.h>

#define NROWS 2048
#define KDIM  128
#define NCELL 16
#define PORD  10
#define NGRAM 512
#define NEVAL 256
#define NBLK3 (NGRAM + NEVAL)

typedef float f32x4  __attribute__((ext_vector_type(4)));
typedef short bf16x8 __attribute__((ext_vector_type(8)));

__device__ __forceinline__ float fexp2(float x){ return __builtin_amdgcn_exp2f(x); }
__device__ __forceinline__ float flog2(float x){ return __builtin_amdgcn_logf(x); }

// sqrt(1/(2*ln2)): exp2(-((t*CS)^2)) = exp(-t^2/2)
#define CS 0.8493218002880191f

// ws float layout
#define OFF_PART   0            // 32*256 partial col sums
#define OFF_ACCUM  8192         // 256 final col sums
#define OFF_JOINT  8448         // 2048
#define OFF_SLOG   10496        // 2048
#define OFF_NRM    12544        // 2048  (joint+slog+nrm = 6144 zeroed by K1)
#define OFF_MOM    14592        // [(c*10+m)*128 + k], 20480 (plain stores, no zero)
#define OFF_CTR    35072        // 1 uint
#define OFF_XT     35076        // float[128][2048] transpose = 262144
#define OFF_XS     297220       // ushort[2048*128]; byte 1188880 (16B aligned)

__device__ __forceinline__ void col_stats_from(float s, float s2, float& scale, float& shift){
  float m = s * (1.f / NROWS);
  float var = fmaxf((s2 - (float)NROWS * m * m) * (1.f / (NROWS - 1)), 0.f);
  scale = 1.f / (sqrtf(var) + 1e-6f);
  shift = -m * scale;
}

// e^{-s^2/2} * sum_m q_m He_m(s)
__device__ __forceinline__ float hermCell(float s,
    float q0, float q1, float q2, float q3, float q4,
    float q5, float q6, float q7, float q8, float q9){
  float scl = s * CS;
  float e = fexp2(-(scl * scl));
  float prev = 1.f, cur = s, nxt;
  float inner = fmaf(q1, s, q0);
  nxt = fmaf(s, cur, -1.f * prev); inner = fmaf(q2, nxt, inner); prev = cur; cur = nxt;
  nxt = fmaf(s, cur, -2.f * prev); inner = fmaf(q3, nxt, inner); prev = cur; cur = nxt;
  nxt = fmaf(s, cur, -3.f * prev); inner = fmaf(q4, nxt, inner); prev = cur; cur = nxt;
  nxt = fmaf(s, cur, -4.f * prev); inner = fmaf(q5, nxt, inner); prev = cur; cur = nxt;
  nxt = fmaf(s, cur, -5.f * prev); inner = fmaf(q6, nxt, inner); prev = cur; cur = nxt;
  nxt = fmaf(s, cur, -6.f * prev); inner = fmaf(q7, nxt, inner); prev = cur; cur = nxt;
  nxt = fmaf(s, cur, -7.f * prev); inner = fmaf(q8, nxt, inner); prev = cur; cur = nxt;
  nxt = fmaf(s, cur, -8.f * prev); inner = fmaf(q9, nxt, inner);
  return e * inner;
}

// ---------------- K1: partial col sums + transpose + zeroing -----------------
__global__ __launch_bounds__(1024) void tc_stats(const float* __restrict__ x,
                                                 float* __restrict__ ws){
  const int t  = threadIdx.x;
  const int k  = t & 127;
  const int rg = t >> 7;
  const int r0 = blockIdx.x * 64;
  {
    int idx = blockIdx.x * 1024 + t;
    if (idx < 6144) ws[OFF_JOINT + idx] = 0.f;          // joint+slog+nrm
    if (idx == 6144) *(unsigned int*)(ws + OFF_CTR) = 0u;
  }
  float s = 0.f, s2 = 0.f;
  #pragma unroll
  for (int it = 0; it < 8; ++it){
    const int row = r0 + it * 8 + rg;
    float v = x[(size_t)row * KDIM + k];
    s += v;
    s2 = fmaf(v, v, s2);
    ws[OFF_XT + (size_t)k * NROWS + row] = v;           // transpose (scatter)
  }
  __shared__ float ls[8][128], ls2[8][128];
  ls[rg][k] = s; ls2[rg][k] = s2;
  __syncthreads();
  if (t < 128){
    float a = 0.f, b = 0.f;
    #pragma unroll
    for (int g = 0; g < 8; ++g){ a += ls[g][t]; b += ls2[g][t]; }
    ws[OFF_PART + blockIdx.x * 256 + t]       = a;
    ws[OFF_PART + blockIdx.x * 256 + 128 + t] = b;
  }
}

// ---------------- K2: per-k moments + bf16 pack + row norms ------------------
// 128 blocks (one per k) x 1024 thr; thread handles rows {t, t+1024}. Coalesced xT.
__global__ __launch_bounds__(1024) void tc_moments(float* __restrict__ ws){
  const int k = blockIdx.x;
  const int t = threadIdx.x;
  const int wave = t >> 6;
  __shared__ float lm[16][NCELL * PORD];   // wave-privatized buckets, 10 KB
  for (int i = t; i < 16 * NCELL * PORD; i += 1024) ((float*)lm)[i] = 0.f;

  // partial reduce: uniform addresses -> scalar loads
  float s = 0.f, s2 = 0.f;
  #pragma unroll
  for (int b = 0; b < 32; ++b){
    s  += ws[OFF_PART + b * 256 + k];
    s2 += ws[OFF_PART + b * 256 + 128 + k];
  }
  if (t == 0){
    ws[OFF_ACCUM + k]       = s;
    ws[OFF_ACCUM + 128 + k] = s2;
  }
  float scale, shift; col_stats_from(s, s2, scale, shift);
  __syncthreads();

  #pragma unroll
  for (int half = 0; half < 2; ++half){
    const int row = t + half * 1024;
    float y = fmaf(ws[OFF_XT + (size_t)k * NROWS + row], scale, shift);
    // CS-folded bf16 pack + bf16-consistent norm
    __hip_bfloat16 hb = __float2bfloat16(y * CS);
    unsigned short us = *(unsigned short*)&hb;
    ((unsigned short*)(ws + OFF_XS))[(size_t)row * KDIM + k] = us;
    float ybf = __builtin_bit_cast(float, (unsigned int)us << 16);
    atomicAdd(&ws[OFF_NRM + row], ybf * ybf);
    // moment scatter into this wave's bucket
    int c = (int)floorf(y * 2.f + 8.f);
    c = min(max(c, 0), NCELL - 1);
    float u = y - (-3.75f + 0.5f * (float)c);
    float* mm = &lm[wave][c * PORD];
    atomicAdd(&mm[0], 1.f);
    float pw = u;
    atomicAdd(&mm[1], pw);
    pw *= u; atomicAdd(&mm[2], pw * 0.5f);
    pw *= u; atomicAdd(&mm[3], pw * 1.6666666666e-1f);
    pw *= u; atomicAdd(&mm[4], pw * 4.1666666666e-2f);
    pw *= u; atomicAdd(&mm[5], pw * 8.3333333333e-3f);
    pw *= u; atomicAdd(&mm[6], pw * 1.3888888889e-3f);
    pw *= u; atomicAdd(&mm[7], pw * 1.9841269841e-4f);
    pw *= u; atomicAdd(&mm[8], pw * 2.4801587302e-5f);
    pw *= u; atomicAdd(&mm[9], pw * 2.7557319224e-6f);
  }
  __syncthreads();

  // combine 16 buckets; plain store (single owner per k)
  for (int i = t; i < NCELL * PORD; i += 1024){
    float a = 0.f;
    #pragma unroll
    for (int w = 0; w < 16; ++w) a += lm[w][i];
    ws[OFF_MOM + (size_t)i * KDIM + k] = a;
  }
}

// ---------------- K3: heterogeneous -- MFMA Gram | FGT eval | finalize -------
__global__ __launch_bounds__(512) void tc_joint(const float* __restrict__ x,
                                                float* __restrict__ ws,
                                                float* __restrict__ out){
  __shared__ float red2[8];
  __shared__ int lastflag;
  const int t = threadIdx.x;
  const int wave = t >> 6, lane = t & 63;
  const int bid = blockIdx.x;
  float* joint = ws + OFF_JOINT;
  float* slog  = ws + OFF_SLOG;
  const float* nrm   = ws + OFF_NRM;
  const float* accum = ws + OFF_ACCUM;
  const float* mom   = ws + OFF_MOM;
  const unsigned short* xs = (const unsigned short*)(ws + OFF_XS);

  if (bid < NGRAM){
    const int bi = bid >> 5, bj = bid & 31;
    const int Ibase = bi * 128, Jbase = bj * 64;
    const int wi = wave >> 2, wj = wave & 3;
    const int lr = lane & 15, hs = lane >> 4;

    f32x4 acc0 = {0.f,0.f,0.f,0.f}, acc1 = acc0, acc2 = acc0, acc3 = acc0;
    #pragma unroll
    for (int kq = 0; kq < 4; ++kq){
      const int co = kq * 32 + hs * 8;   // ushort col offset (16B aligned)
      bf16x8 bf = *(const bf16x8*)(xs + (size_t)(Jbase + wj * 16 + lr) * KDIM + co);
      bf16x8 a0 = *(const bf16x8*)(xs + (size_t)(Ibase + wi * 64 + lr +  0) * KDIM + co);
      bf16x8 a1 = *(const bf16x8*)(xs + (size_t)(Ibase + wi * 64 + lr + 16) * KDIM + co);
      bf16x8 a2 = *(const bf16x8*)(xs + (size_t)(Ibase + wi * 64 + lr + 32) * KDIM + co);
      bf16x8 a3 = *(const bf16x8*)(xs + (size_t)(Ibase + wi * 64 + lr + 48) * KDIM + co);
      acc0 = __builtin_amdgcn_mfma_f32_16x16x32_bf16(a0, bf, acc0, 0, 0, 0);
      acc1 = __builtin_amdgcn_mfma_f32_16x16x32_bf16(a1, bf, acc1, 0, 0, 0);
      acc2 = __builtin_amdgcn_mfma_f32_16x16x32_bf16(a2, bf, acc2, 0, 0, 0);
      acc3 = __builtin_amdgcn_mfma_f32_16x16x32_bf16(a3, bf, acc3, 0, 0, 0);
    }

    const float njv = nrm[Jbase + wj * 16 + lr];
    const int rbase = hs * 4;
    float jp[4][4];
    #pragma unroll
    for (int mt = 0; mt < 4; ++mt){
      f32x4 a4 = (mt == 0) ? acc0 : (mt == 1) ? acc1 : (mt == 2) ? acc2 : acc3;
      const float4 nI4 = *(const float4*)(nrm + Ibase + wi * 64 + mt * 16 + rbase);
      jp[mt][0] = fexp2(-(nI4.x + njv - 2.f * a4[0]));
      jp[mt][1] = fexp2(-(nI4.y + njv - 2.f * a4[1]));
      jp[mt][2] = fexp2(-(nI4.z + njv - 2.f * a4[2]));
      jp[mt][3] = fexp2(-(nI4.w + njv - 2.f * a4[3]));
    }
    #pragma unroll
    for (int mt = 0; mt < 4; ++mt){
      #pragma unroll
      for (int p = 0; p < 4; ++p){
        float v = jp[mt][p];
        v += __shfl_xor(v, 1); v += __shfl_xor(v, 2);
        v += __shfl_xor(v, 4); v += __shfl_xor(v, 8);
        jp[mt][p] = v;
      }
    }
    if (lr == 0){
      #pragma unroll
      for (int mt = 0; mt < 4; ++mt)
        #pragma unroll
        for (int p = 0; p < 4; ++p)
          atomicAdd(&joint[Ibase + wi * 64 + mt * 16 + rbase + p], jp[mt][p]);
    }
  } else {
    // ---- FGT eval: 8 rows per block; thread (k=t&127, irg=t>>7) -> 2 rows ----
    const int k = t & 127, irg = t >> 7;
    const int r0 = (bid - NGRAM) * 8 + irg * 2;
    float scale, shift;
    col_stats_from(accum[k], accum[128 + k], scale, shift);
    const float y0 = fmaf(x[(size_t)r0 * KDIM + k],       scale, shift);
    const float y1 = fmaf(x[(size_t)(r0 + 1) * KDIM + k], scale, shift);
    float S0 = 0.f, S1 = 0.f;
    #pragma unroll
    for (int c = 0; c < NCELL; ++c){
      const float* mp = mom + (size_t)c * PORD * KDIM + k;   // coalesced scalars
      const float q0 = mp[0 * KDIM], q1 = mp[1 * KDIM], q2 = mp[2 * KDIM];
      const float q3 = mp[3 * KDIM], q4 = mp[4 * KDIM], q5 = mp[5 * KDIM];
      const float q6 = mp[6 * KDIM], q7 = mp[7 * KDIM], q8 = mp[8 * KDIM];
      const float q9 = mp[9 * KDIM];
      const float ctr = -3.75f + 0.5f * (float)c;
      S0 += hermCell(y0 - ctr, q0,q1,q2,q3,q4,q5,q6,q7,q8,q9);
      S1 += hermCell(y1 - ctr, q0,q1,q2,q3,q4,q5,q6,q7,q8,q9);
    }
    float lg0 = flog2(S0), lg1 = flog2(S1);
    #pragma unroll
    for (int off = 1; off < 64; off <<= 1){
      lg0 += __shfl_xor(lg0, off);
      lg1 += __shfl_xor(lg1, off);
    }
    if (lane == 0){
      atomicAdd(&slog[r0],     lg0);
      atomicAdd(&slog[r0 + 1], lg1);
    }
  }

  // ---- arrival counter; last block finalizes ----
  __syncthreads();
  if (t == 0){
    __threadfence();
    unsigned int* ctr = (unsigned int*)(ws + OFF_CTR);
    unsigned int old = __hip_atomic_fetch_add(ctr, 1u, __ATOMIC_ACQ_REL, __HIP_MEMORY_SCOPE_AGENT);
    lastflag = (old == NBLK3 - 1);
  }
  __syncthreads();
  if (lastflag){
    float acc = 0.f;
    #pragma unroll
    for (int q = 0; q < 4; ++q){
      int r = q * 512 + t;
      float jv = __hip_atomic_load(&joint[r], __ATOMIC_RELAXED, __HIP_MEMORY_SCOPE_AGENT);
      float sv = __hip_atomic_load(&slog[r],  __ATOMIC_RELAXED, __HIP_MEMORY_SCOPE_AGENT);
      acc += 0.6931471805599453f * (flog2(jv) - sv);
    }
    #pragma unroll
    for (int m = 1; m < 64; m <<= 1) acc += __shfl_xor(acc, m);
    if (lane == 0) red2[wave] = acc;
    __syncthreads();
    if (t == 0){
      float tot = 0.f;
      #pragma unroll
      for (int w = 0; w < 8; ++w) tot += red2[w];
      out[0] = tot * (1.0f / NROWS) + 968.32661124224364f;  // +127*ln(2048)
    }
  }
}

// ---------------- launch -----------------------------------------------------
extern "C" void kernel_launch(void* const* d_in, const int* in_sizes, int n_in,
                              void* d_out, int out_size, void* d_ws, size_t ws_size,
                              hipStream_t stream){
  const float* x = (const float*)d_in[0];
  float* out = (float*)d_out;
  float* ws  = (float*)d_ws;
  tc_stats  <<<32, 1024, 0, stream>>>(x, ws);
  tc_moments<<<KDIM, 1024, 0, stream>>>(ws);
  tc_joint  <<<NBLK3, 512, 0, stream>>>(x, ws, out);
}